// Round 11
// baseline (214.924 us; speedup 1.0000x reference)
//
#include <hip/hip_runtime.h>
#include <cstdint>
#include <math.h>

#define G 64
#define S 32
#define G3 (G*G*G)
#define S3 (S*S*S)

typedef unsigned long long u64;
typedef unsigned int u32;
typedef unsigned short u16;

typedef __attribute__((ext_vector_type(8))) short s16x8;   // 8 bf16 (4 VGPRs)
typedef __attribute__((ext_vector_type(4))) float f32x4;   // MFMA acc

__device__ __forceinline__ float sigmoidf_(float v) {
    return 1.0f / (1.0f + expf(-v));
}
__device__ __forceinline__ u32 f2bf_rne(float f) {   // round-to-nearest-even bf16
    u32 u = __float_as_uint(f);
    u += 0x7fff + ((u >> 16) & 1);
    return u >> 16;
}
__device__ __forceinline__ u64 rfl64(u64 v) {
    u32 lo = __builtin_amdgcn_readfirstlane((u32)v);
    u32 hi = __builtin_amdgcn_readfirstlane((u32)(v >> 32));
    return ((u64)hi << 32) | lo;
}
__device__ __forceinline__ u64 tap_hit(u64 wout, u64 wn, int dz) {
    return (dz >= 0) ? (wout & (wn >> dz)) : (wout & (wn << (-dz)));
}

// ---------------------------------------------------------------- parent occupancy
__global__ __launch_bounds__(256) void k_pocc(const float* __restrict__ x,
                                              unsigned char* __restrict__ pocc) {
    int p = blockIdx.x * 256 + threadIdx.x;
    if (p >= S3) return;
    int pz = p & 31, py = (p >> 5) & 31, px = p >> 10;
    const float* b = x + (((size_t)(px * 2) * G + py * 2) * G + pz * 2);
    bool occ = false;
    #pragma unroll
    for (int a = 0; a < 2; a++)
        #pragma unroll
        for (int bb = 0; bb < 2; bb++)
            #pragma unroll
            for (int c = 0; c < 2; c++)
                occ = occ || (b[((size_t)a * G + bb) * G + c] > 0.0f);
    pocc[p] = occ ? 1 : 0;
}

// ---------------------------------------------------------------- FEL conv1: 1->16, 3^3, relu
__global__ __launch_bounds__(256) void k_fel1(const unsigned char* __restrict__ pocc,
                                              const float* __restrict__ w1,
                                              const float* __restrict__ b1,
                                              float* __restrict__ h1) {
    int p = blockIdx.x * 256 + threadIdx.x;
    if (p >= S3) return;
    int pz = p & 31, py = (p >> 5) & 31, px = p >> 10;
    float* o = h1 + (size_t)p * 16;
    if (!pocc[p]) {
        #pragma unroll
        for (int i = 0; i < 16; i++) o[i] = 0.0f;
        return;
    }
    float acc[16];
    #pragma unroll
    for (int i = 0; i < 16; i++) acc[i] = b1[i];
    for (int dx = -1; dx <= 1; ++dx) {
        int nx = px + dx; if ((unsigned)nx >= S) continue;
        for (int dy = -1; dy <= 1; ++dy) {
            int ny = py + dy; if ((unsigned)ny >= S) continue;
            for (int dz = -1; dz <= 1; ++dz) {
                int nz = pz + dz; if ((unsigned)nz >= S) continue;
                if (pocc[(nx * S + ny) * S + nz]) {
                    const float* w = w1 + (((dx + 1) * 3 + (dy + 1)) * 3 + (dz + 1)) * 16;
                    #pragma unroll
                    for (int i = 0; i < 16; i++) acc[i] += w[i];
                }
            }
        }
    }
    #pragma unroll
    for (int i = 0; i < 16; i++) o[i] = fmaxf(acc[i], 0.0f);
}

// ---------------------------------------------------------------- FEL conv2: 16->16, 3^3
__global__ __launch_bounds__(256) void k_fel2(const unsigned char* __restrict__ pocc,
                                              const float* __restrict__ h1,
                                              const float* __restrict__ w2,
                                              const float* __restrict__ b2,
                                              float* __restrict__ h2) {
    int p = blockIdx.x * 256 + threadIdx.x;
    if (p >= S3) return;
    int pz = p & 31, py = (p >> 5) & 31, px = p >> 10;
    float* o = h2 + (size_t)p * 16;
    if (!pocc[p]) {
        #pragma unroll
        for (int i = 0; i < 16; i++) o[i] = 0.0f;
        return;
    }
    float acc[16];
    #pragma unroll
    for (int i = 0; i < 16; i++) acc[i] = b2[i];
    for (int dx = -1; dx <= 1; ++dx) {
        int nx = px + dx; if ((unsigned)nx >= S) continue;
        for (int dy = -1; dy <= 1; ++dy) {
            int ny = py + dy; if ((unsigned)ny >= S) continue;
            for (int dz = -1; dz <= 1; ++dz) {
                int nz = pz + dz; if ((unsigned)nz >= S) continue;
                const float* f = h1 + (size_t)((nx * S + ny) * S + nz) * 16;
                const float* w = w2 + (((dx + 1) * 3 + (dy + 1)) * 3 + (dz + 1)) * 256;
                #pragma unroll
                for (int ci = 0; ci < 16; ++ci) {
                    float fv = f[ci];
                    #pragma unroll
                    for (int co = 0; co < 16; ++co)
                        acc[co] = fmaf(fv, w[ci * 16 + co], acc[co]);
                }
            }
        }
    }
    #pragma unroll
    for (int i = 0; i < 16; i++) o[i] = acc[i];
}

// ---------------------------------------------------------------- generative up (k2 s2) -> prob_f (bf16, [line][64][16])
__global__ __launch_bounds__(256) void k_up(const unsigned char* __restrict__ pocc,
                                            const float* __restrict__ h2,
                                            const float* __restrict__ wup,
                                            const float* __restrict__ bup,
                                            u16* __restrict__ pf) {
    int p = blockIdx.x * 256 + threadIdx.x;
    if (p >= S3) return;
    int pz = p & 31, py = (p >> 5) & 31, px = p >> 10;
    bool occ = pocc[p] != 0;
    float h[16];
    const float* hp = h2 + (size_t)p * 16;
    #pragma unroll
    for (int i = 0; i < 16; i++) h[i] = hp[i];
    #pragma unroll
    for (int o = 0; o < 8; o++) {
        int a = o >> 2, b = (o >> 1) & 1, c = o & 1;
        u16* op = pf + (((size_t)(2 * px + a) * G + (2 * py + b)) * G + (2 * pz + c)) * 16;
        uint4* o4 = reinterpret_cast<uint4*>(op);
        if (!occ) {
            o4[0] = make_uint4(0, 0, 0, 0);
            o4[1] = make_uint4(0, 0, 0, 0);
        } else {
            u32 pk[8];
            #pragma unroll
            for (int i = 0; i < 8; ++i) {
                float a0 = bup[2 * i], a1 = bup[2 * i + 1];
                #pragma unroll
                for (int cc = 0; cc < 16; cc++) {
                    a0 = fmaf(h[cc], wup[(o * 16 + cc) * 16 + 2 * i], a0);
                    a1 = fmaf(h[cc], wup[(o * 16 + cc) * 16 + 2 * i + 1], a1);
                }
                pk[i] = f2bf_rne(a0) | (f2bf_rne(a1) << 16);
            }
            o4[0] = make_uint4(pk[0], pk[1], pk[2], pk[3]);
            o4[1] = make_uint4(pk[4], pk[5], pk[6], pk[7]);
        }
    }
}

// ---------------------------------------------------------------- masks -> 64-bit line words + labels
__global__ __launch_bounds__(256) void k_masks(const float* __restrict__ x,
                                               const unsigned char* __restrict__ pocc,
                                               u64* __restrict__ lw_in,
                                               u64* __restrict__ lw_fin,
                                               float* __restrict__ labels) {
    int z = threadIdx.x;
    int y = blockIdx.x * 4 + threadIdx.y;
    int xx = blockIdx.y;
    int v = (xx * G + y) * G + z;
    int par = ((xx & 1) << 2) | ((y & 1) << 1) | (z & 1);
    const int gmap[8] = {0, 5, 4, 3, 4, 2, 1, 5};
    int g = gmap[par];
    int t = ((xx >> 1) + (y >> 1) + (z >> 1)) % 3;
    bool occ = pocc[(((xx >> 1) * S) + (y >> 1)) * S + (z >> 1)] != 0;
    bool ox = x[v] > 0.0f;
    bool g0 = (g == 0);

    bool mi[8], mf[8], lb[8];
    mi[0] = occ && g0 && (t == 0);
    mi[1] = (occ && g0 && (t == 1)) || (ox && g0 && (t == 0));
    mi[2] = (ox && g0 && (t < 2)) || (occ && g0 && (t == 2));
    mi[3] = (ox && g0)       || (occ && (g == 1));
    mi[4] = (ox && (g <= 1)) || (occ && (g == 2));
    mi[5] = (ox && (g <= 2)) || (occ && (g == 3));
    mi[6] = (ox && (g <= 3)) || (occ && (g == 4));
    mi[7] = (ox && (g <= 4)) || (occ && (g == 5));

    mf[0] = occ && g0 && (t == 0);
    mf[1] = occ && g0 && (t == 1);
    mf[2] = occ && g0 && (t == 2);
    mf[3] = occ && (g == 1);
    mf[4] = occ && (g == 2);
    mf[5] = occ && (g == 3);
    mf[6] = occ && (g == 4);
    mf[7] = occ && (g == 5);

    lb[0] = ox && g0 && (t == 0);
    lb[1] = ox && g0 && (t == 1);
    lb[2] = ox && g0 && (t == 2);
    lb[3] = ox && (g == 1);
    lb[4] = ox && (g == 2);
    lb[5] = ox && (g == 3);
    lb[6] = ox && (g == 4);
    lb[7] = ox && (g == 5);

    int line = xx * G + y;
    #pragma unroll
    for (int c = 0; c < 8; ++c) {
        u64 wi = __ballot((int)mi[c]);
        u64 wf = __ballot((int)mf[c]);
        if (z == 0) {
            lw_in[c * 4096 + line] = wi;
            lw_fin[c * 4096 + line] = wf;
        }
        labels[(size_t)c * G3 + v] = lb[c] ? 1.0f : 0.0f;
    }
}

// ---------------------------------------------------------------- B-fragment prep (weights -> MFMA lane layout, bf16)
// frag index = ((dxi*KS)+dyi)*npair + p ; k<16 -> dz_A = -R+2p ; k>=16 -> dz_B = dz_A+1 (zero weight if OOB)
#define FRAGSTRIDE 38400   // u16 per coder (75 frags * 64 lanes * 8)
__global__ __launch_bounds__(64) void k_prep_bfrag(const float* __restrict__ wc1,
                                                   const float* __restrict__ wl1,
                                                   u16* __restrict__ bfrag) {
    int c = blockIdx.x;
    int frag = blockIdx.y;
    int lane = threadIdx.x;
    bool is5 = (c == 1 || c == 2);
    int R = is5 ? 2 : 1;
    int KS = 2 * R + 1;
    int npair = R + 1;
    int nfrag = KS * KS * npair;
    if (frag >= nfrag) return;
    const float* W = is5 ? (wl1 + (size_t)(c - 1) * 32000)
                         : (wc1 + (size_t)((c == 0) ? 0 : (c - 2)) * 6912);
    int dxdy = frag / npair, p = frag - dxdy * npair;
    int dziA = 2 * p;
    int co = lane & 15, kg = lane >> 4;
    u16 outv[8];
    #pragma unroll
    for (int j = 0; j < 8; ++j) {
        int k = kg * 8 + j;
        int ci = k & 15;
        int dzi = (k < 16) ? dziA : (dziA + 1);
        float v = 0.0f;
        if (dzi < KS)
            v = W[(size_t)(dxdy * KS + dzi) * 256 + ci * 16 + co];
        outv[j] = (u16)f2bf_rne(v);
    }
    u16* o = bfrag + (size_t)c * FRAGSTRIDE + ((size_t)frag * 64 + lane) * 8;
    uint4 pk;
    pk.x = outv[0] | ((u32)outv[1] << 16);
    pk.y = outv[2] | ((u32)outv[3] << 16);
    pk.z = outv[4] | ((u32)outv[5] << 16);
    pk.w = outv[6] | ((u32)outv[7] << 16);
    *reinterpret_cast<uint4*>(o) = pk;
}

// ---------------------------------------------------------------- conv1 via MFMA (r4 schedule + XOR-half LDS swizzle)
// WG = 4 waves, each wave owns one output z-line (x, y0+w). LDS stages (4+2R) masked,
// z-padded lines per dx. Slot layout: voxel lz, half h -> byte = s*2304 + lz*32 + ((h^((lz>>2)&1))*16).
// Both ds_write (staging) and ds_read (A-fragments) use the same involution -> ~0 bank conflicts.
__global__ __launch_bounds__(256) void k_conv1_mfma(const u16* __restrict__ pf,
                                                    const u64* __restrict__ lw_in,
                                                    const u16* __restrict__ bfrag,
                                                    const float* __restrict__ bc1,
                                                    const float* __restrict__ bl1,
                                                    u16* __restrict__ hbase) {
    int c = blockIdx.y;
    bool is5 = (c == 1 || c == 2);
    int R = is5 ? 2 : 1;
    int KS = 2 * R + 1, npair = R + 1;
    const u64* lw = lw_in + (size_t)c * 4096;
    u16* h_c = hbase + (size_t)c * G3 * 16;
    const u16* bf = bfrag + (size_t)c * FRAGSTRIDE;
    const float* bptr = is5 ? (bl1 + (c - 1) * 16)
                            : (bc1 + ((c == 0) ? 0 : (c - 2)) * 16);

    int x = blockIdx.x >> 4;
    int y0 = (blockIdx.x & 15) << 2;
    int w = threadIdx.y;
    int lane = threadIdx.x;
    int yw = y0 + w;

    u64 w0 = rfl64(lw[x * G + yw]);
    u64 anyw = lw[x * G + y0] | lw[x * G + y0 + 1] | lw[x * G + y0 + 2] | lw[x * G + y0 + 3];
    if (anyw == 0ULL) return;          // uniform across WG: safe early-out (before barriers)

    __shared__ u32 lds[8 * 2304 / 4];  // 18432 B

    int col = lane & 15, kg = lane >> 4;
    float bv = bptr[col];
    f32x4 acc[4];
    #pragma unroll
    for (int s = 0; s < 4; ++s) acc[s] = (f32x4){bv, bv, bv, bv};

    int nlines = 4 + 2 * R;
    int nunits = nlines * 144;         // 72 lz * 2 halves per line
    int t = w * 64 + lane;

    for (int dx = -R; dx <= R; ++dx) {
        int nx = x + dx;
        __syncthreads();
        if ((unsigned)nx < G) {
            for (int u = t; u < nunits; u += 256) {
                int s = u / 144; int q = u - s * 144;
                int lz = q >> 1, half = q & 1;
                int gz = lz - 4;
                int ny = y0 - R + s;
                uint4 val = make_uint4(0, 0, 0, 0);
                if ((unsigned)ny < G && (unsigned)gz < G) {
                    u64 wn = lw[nx * G + ny];
                    if ((wn >> gz) & 1)
                        val = *reinterpret_cast<const uint4*>(
                            pf + ((size_t)((nx * G + ny) * G + gz) * 16 + half * 8));
                }
                *reinterpret_cast<uint4*>(
                    reinterpret_cast<char*>(lds) + s * 2304 + lz * 32 +
                    ((half ^ ((lz >> 2) & 1)) * 16)) = val;
            }
        }
        __syncthreads();
        if (w0 == 0ULL || (unsigned)nx >= G) continue;

        for (int dy = -R; dy <= R; ++dy) {
            int ny = yw + dy;
            if ((unsigned)ny >= G) continue;
            u64 wn = rfl64(lw[nx * G + ny]);
            if (wn == 0ULL) continue;
            int slot = w + dy + R;
            for (int p = 0; p < npair; ++p) {
                int dzA = -R + 2 * p;
                int dzB = dzA + 1;
                bool hasB = (dzB <= R);
                u64 hit = tap_hit(w0, wn, dzA);
                if (hasB) hit |= tap_hit(w0, wn, dzB);
                if (hit == 0ULL) continue;
                int frag = ((dx + R) * KS + (dy + R)) * npair + p;
                s16x8 bf8 = *reinterpret_cast<const s16x8*>(bf + ((size_t)frag * 64 + lane) * 8);
                int dz = (kg < 2) ? dzA : (hasB ? dzB : dzA);
                int lzb = col + dz + 4;
                const char* ab = reinterpret_cast<const char*>(lds)
                                 + slot * 2304 + lzb * 32
                                 + (((kg & 1) ^ ((lzb >> 2) & 1)) * 16);
                #pragma unroll
                for (int s = 0; s < 4; ++s) {
                    if (((hit >> (s * 16)) & 0xFFFFULL) == 0ULL) continue;
                    s16x8 a = *reinterpret_cast<const s16x8*>(ab + s * 512);
                    acc[s] = __builtin_amdgcn_mfma_f32_16x16x32_bf16(a, bf8, acc[s], 0, 0, 0);
                }
            }
        }
    }

    if (w0 == 0ULL) return;
    u16* hline = h_c + (size_t)(x * G + yw) * G * 16;
    #pragma unroll
    for (int s = 0; s < 4; ++s) {
        #pragma unroll
        for (int r = 0; r < 4; ++r) {
            int z = s * 16 + kg * 4 + r;
            if ((w0 >> z) & 1) {
                float v = fmaxf(acc[s][r], 0.0f);
                hline[z * 16 + col] = (u16)f2bf_rne(v);
            }
        }
    }
}

// ---------------------------------------------------------------- coder conv2 body (C->1, K^3, sigmoid) + ILP acc split
template <int KS>
__device__ __forceinline__ void conv2_body(const u32* __restrict__ h_c,
                                           const u64* __restrict__ lwi,
                                           const u64* __restrict__ lwf,
                                           const float* __restrict__ w2,
                                           const float* __restrict__ b2,
                                           float* __restrict__ outp) {
    const int R = KS / 2;
    int z = threadIdx.x;
    int line = blockIdx.x * 4 + threadIdx.y;
    int xx = line >> 6, y = line & 63;
    int v = (xx * G + y) * G + z;
    u64 wf = rfl64(lwf[line]);
    if (wf == 0ULL) { outp[v] = 0.0f; return; }
    bool m = (wf >> z) & 1;

    float ac0 = 0.0f, ac1 = 0.0f;
    for (int dx = -R; dx <= R; ++dx) {
        int nx = xx + dx; if ((unsigned)nx >= G) continue;
        for (int dy = -R; dy <= R; ++dy) {
            int ny = y + dy; if ((unsigned)ny >= G) continue;
            u64 wn = rfl64(lwi[nx * G + ny]);
            if (wn == 0ULL) continue;
            const float* wbase = w2 + (size_t)(((dx + R) * KS + (dy + R)) * KS) * 16;
            #pragma unroll
            for (int dz = -R; dz <= R; ++dz) {
                if (tap_hit(wf, wn, dz) == 0ULL) continue;
                int nz = z + dz;
                bool ok = (unsigned)nz < G;
                int nzc = ok ? nz : 0;
                bool mn = ok && ((wn >> nzc) & 1);
                const float* w = wbase + (dz + R) * 16;
                if (mn) {
                    const uint4* h4 = reinterpret_cast<const uint4*>(
                        h_c + ((size_t)((nx * G + ny) * G + nzc)) * 8);
                    uint4 Ua = h4[0], Ub = h4[1];
                    u32 uu[8] = {Ua.x, Ua.y, Ua.z, Ua.w, Ub.x, Ub.y, Ub.z, Ub.w};
                    float s0 = 0.0f, s1 = 0.0f;
                    #pragma unroll
                    for (int i = 0; i < 8; ++i) {
                        float lo = __uint_as_float(uu[i] << 16);
                        float hi = __uint_as_float(uu[i] & 0xffff0000u);
                        s0 = fmaf(lo, w[2 * i], s0);
                        s1 = fmaf(hi, w[2 * i + 1], s1);
                    }
                    if (((dz + R) & 1) == 0) ac0 += s0 + s1;   // compile-time select (dz unrolled)
                    else                     ac1 += s0 + s1;
                }
            }
        }
    }
    float acc = b2[0] + ac0 + ac1;
    outp[v] = m ? sigmoidf_(acc) : 0.0f;
}

__global__ __launch_bounds__(256) void k_conv2_all(const u32* __restrict__ hbase,
                                                   const u64* __restrict__ lw_in,
                                                   const u64* __restrict__ lw_fin,
                                                   const float* __restrict__ wc2,
                                                   const float* __restrict__ bc2,
                                                   const float* __restrict__ wl2,
                                                   const float* __restrict__ bl2,
                                                   float* __restrict__ out) {
    int c = blockIdx.y;
    const u64* lwi = lw_in + (size_t)c * 4096;
    const u64* lwf = lw_fin + (size_t)c * 4096;
    const u32* h_c = hbase + (size_t)c * G3 * 8;
    float* outp = out + (size_t)c * G3;
    if (c == 1 || c == 2) {
        conv2_body<5>(h_c, lwi, lwf, wl2 + (size_t)(c - 1) * 2000, bl2 + (c - 1), outp);
    } else {
        int j = (c == 0) ? 0 : (c - 2);
        conv2_body<3>(h_c, lwi, lwf, wc2 + (size_t)j * 432, bc2 + j, outp);
    }
}

// ---------------------------------------------------------------- launch
extern "C" void kernel_launch(void* const* d_in, const int* in_sizes, int n_in,
                              void* d_out, int out_size, void* d_ws, size_t ws_size,
                              hipStream_t stream) {
    const float* x      = (const float*)d_in[0];
    const float* w_fel1 = (const float*)d_in[3];
    const float* b_fel1 = (const float*)d_in[4];
    const float* w_fel2 = (const float*)d_in[5];
    const float* b_fel2 = (const float*)d_in[6];
    const float* w_up   = (const float*)d_in[7];
    const float* b_up   = (const float*)d_in[8];
    const float* wc1    = (const float*)d_in[9];
    const float* bc1    = (const float*)d_in[10];
    const float* wc2    = (const float*)d_in[11];
    const float* bc2    = (const float*)d_in[12];
    const float* wl1    = (const float*)d_in[13];
    const float* bl1    = (const float*)d_in[14];
    const float* wl2    = (const float*)d_in[15];
    const float* bl2    = (const float*)d_in[16];
    float* out = (float*)d_out;

    char* ws = (char*)d_ws;
    u16*  probf16 = (u16*)(ws);                            // 8 MB  bf16[4096 lines][64][16]
    float* h1     = (float*)(ws + 8388608);                // 2 MB
    float* h2     = (float*)(ws + 10485760);               // 2 MB
    unsigned char* pocc = (unsigned char*)(ws + 12582912); // 32 KB
    u64* lw_in  = (u64*)(ws + 12615680);                   // 256 KB
    u64* lw_fin = (u64*)(ws + 12877824);                   // 256 KB
    u16* bfrag  = (u16*)(ws + 13139968);                   // 600 KB
    u16* hbase  = (u16*)(ws + 13754368);                   // 64 MB (8 coders x 8 MB bf16 h)
    // footprint 77.9 MB — proven fits (r7-r9 passed with identical extent)

    k_pocc <<<dim3(S3 / 256), dim3(256), 0, stream>>>(x, pocc);
    k_fel1 <<<dim3(S3 / 256), dim3(256), 0, stream>>>(pocc, w_fel1, b_fel1, h1);
    k_fel2 <<<dim3(S3 / 256), dim3(256), 0, stream>>>(pocc, h1, w_fel2, b_fel2, h2);
    k_up   <<<dim3(S3 / 256), dim3(256), 0, stream>>>(pocc, h2, w_up, b_up, probf16);
    k_masks<<<dim3(16, 64), dim3(64, 4), 0, stream>>>(x, pocc, lw_in, lw_fin, out + (size_t)8 * G3);
    k_prep_bfrag<<<dim3(8, 75), dim3(64), 0, stream>>>(wc1, wl1, bfrag);

    k_conv1_mfma<<<dim3(1024, 8), dim3(64, 4), 0, stream>>>(
        probf16, lw_in, bfrag, bc1, bl1, hbase);
    k_conv2_all<<<dim3(1024, 8), dim3(64, 4), 0, stream>>>(
        (const u32*)hbase, lw_in, lw_fin, wc2, bc2, wl2, bl2, out);
}

// Round 13
// 210.907 us; speedup vs baseline: 1.0190x; 1.0190x over previous
//
#include <hip/hip_runtime.h>
#include <cstdint>
#include <math.h>

#define G 64
#define S 32
#define G3 (G*G*G)
#define S3 (S*S*S)

typedef unsigned long long u64;
typedef unsigned int u32;
typedef unsigned short u16;

typedef __attribute__((ext_vector_type(8))) short s16x8;   // 8 bf16 (4 VGPRs)
typedef __attribute__((ext_vector_type(4))) float f32x4;   // MFMA acc

__device__ __forceinline__ float sigmoidf_(float v) {
    return 1.0f / (1.0f + expf(-v));
}
__device__ __forceinline__ u32 f2bf_rne(float f) {   // round-to-nearest-even bf16
    u32 u = __float_as_uint(f);
    u += 0x7fff + ((u >> 16) & 1);
    return u >> 16;
}
__device__ __forceinline__ u64 rfl64(u64 v) {
    u32 lo = __builtin_amdgcn_readfirstlane((u32)v);
    u32 hi = __builtin_amdgcn_readfirstlane((u32)(v >> 32));
    return ((u64)hi << 32) | lo;
}
__device__ __forceinline__ u64 tap_hit(u64 wout, u64 wn, int dz) {
    return (dz >= 0) ? (wout & (wn >> dz)) : (wout & (wn << (-dz)));
}
// async global->LDS, 16B per lane; dest = base + lane*16 (wave-uniform base)
__device__ __forceinline__ void gload16(const void* g, void* l) {
    __builtin_amdgcn_global_load_lds(
        (const __attribute__((address_space(1))) unsigned int*)g,
        (__attribute__((address_space(3))) unsigned int*)l, 16, 0, 0);
}

// ---------------------------------------------------------------- parent occupancy
__global__ __launch_bounds__(256) void k_pocc(const float* __restrict__ x,
                                              unsigned char* __restrict__ pocc) {
    int p = blockIdx.x * 256 + threadIdx.x;
    if (p >= S3) return;
    int pz = p & 31, py = (p >> 5) & 31, px = p >> 10;
    const float* b = x + (((size_t)(px * 2) * G + py * 2) * G + pz * 2);
    bool occ = false;
    #pragma unroll
    for (int a = 0; a < 2; a++)
        #pragma unroll
        for (int bb = 0; bb < 2; bb++)
            #pragma unroll
            for (int c = 0; c < 2; c++)
                occ = occ || (b[((size_t)a * G + bb) * G + c] > 0.0f);
    pocc[p] = occ ? 1 : 0;
}

// ---------------------------------------------------------------- FEL conv1: 1->16, 3^3, relu  (thread = (p, co))
__global__ __launch_bounds__(256) void k_fel1(const unsigned char* __restrict__ pocc,
                                              const float* __restrict__ w1,
                                              const float* __restrict__ b1,
                                              float* __restrict__ h1) {
    int idx = blockIdx.x * 256 + threadIdx.x;       // S3*16
    int p = idx >> 4, co = idx & 15;
    int pz = p & 31, py = (p >> 5) & 31, px = p >> 10;
    if (!pocc[p]) { h1[idx] = 0.0f; return; }
    float a = b1[co];
    for (int dx = -1; dx <= 1; ++dx) {
        int nx = px + dx; if ((unsigned)nx >= S) continue;
        for (int dy = -1; dy <= 1; ++dy) {
            int ny = py + dy; if ((unsigned)ny >= S) continue;
            for (int dz = -1; dz <= 1; ++dz) {
                int nz = pz + dz; if ((unsigned)nz >= S) continue;
                if (pocc[(nx * S + ny) * S + nz])
                    a += w1[(((dx + 1) * 3 + (dy + 1)) * 3 + (dz + 1)) * 16 + co];
            }
        }
    }
    h1[idx] = fmaxf(a, 0.0f);
}

// ---------------------------------------------------------------- FEL conv2: 16->16, 3^3  (thread = (p, co))
__global__ __launch_bounds__(256) void k_fel2(const unsigned char* __restrict__ pocc,
                                              const float* __restrict__ h1,
                                              const float* __restrict__ w2,
                                              const float* __restrict__ b2,
                                              float* __restrict__ h2) {
    int idx = blockIdx.x * 256 + threadIdx.x;       // S3*16
    int p = idx >> 4, co = idx & 15;
    int pz = p & 31, py = (p >> 5) & 31, px = p >> 10;
    if (!pocc[p]) { h2[idx] = 0.0f; return; }
    float a = b2[co];
    for (int dx = -1; dx <= 1; ++dx) {
        int nx = px + dx; if ((unsigned)nx >= S) continue;
        for (int dy = -1; dy <= 1; ++dy) {
            int ny = py + dy; if ((unsigned)ny >= S) continue;
            for (int dz = -1; dz <= 1; ++dz) {
                int nz = pz + dz; if ((unsigned)nz >= S) continue;
                const float* f = h1 + (size_t)((nx * S + ny) * S + nz) * 16;
                const float* ww = w2 + (size_t)(((dx + 1) * 3 + (dy + 1)) * 3 + (dz + 1)) * 256 + co;
                #pragma unroll
                for (int ci = 0; ci < 16; ++ci)
                    a = fmaf(f[ci], ww[ci * 16], a);
            }
        }
    }
    h2[idx] = a;
}

// ---------------------------------------------------------------- generative up (k2 s2) -> prob_f (bf16, [line][64][16])  (thread = (p, o))
__global__ __launch_bounds__(256) void k_up(const unsigned char* __restrict__ pocc,
                                            const float* __restrict__ h2,
                                            const float* __restrict__ wup,
                                            const float* __restrict__ bup,
                                            u16* __restrict__ pf) {
    int idx = blockIdx.x * 256 + threadIdx.x;       // S3*8
    int p = idx >> 3, o = idx & 7;
    int pz = p & 31, py = (p >> 5) & 31, px = p >> 10;
    bool occ = pocc[p] != 0;
    int a = o >> 2, b = (o >> 1) & 1, c = o & 1;
    int line = (2 * px + a) * G + (2 * py + b);
    u16* op = pf + ((size_t)line * 64 + (2 * pz + c)) * 16;
    uint4* o4 = reinterpret_cast<uint4*>(op);
    if (!occ) {
        o4[0] = make_uint4(0, 0, 0, 0);
        o4[1] = make_uint4(0, 0, 0, 0);
        return;
    }
    float h[16];
    const float* hp = h2 + (size_t)p * 16;
    #pragma unroll
    for (int i = 0; i < 16; i++) h[i] = hp[i];
    u32 pk[8];
    #pragma unroll
    for (int i = 0; i < 8; ++i) {
        float a0 = bup[2 * i], a1 = bup[2 * i + 1];
        #pragma unroll
        for (int cc = 0; cc < 16; cc++) {
            a0 = fmaf(h[cc], wup[(o * 16 + cc) * 16 + 2 * i], a0);
            a1 = fmaf(h[cc], wup[(o * 16 + cc) * 16 + 2 * i + 1], a1);
        }
        pk[i] = f2bf_rne(a0) | (f2bf_rne(a1) << 16);
    }
    o4[0] = make_uint4(pk[0], pk[1], pk[2], pk[3]);
    o4[1] = make_uint4(pk[4], pk[5], pk[6], pk[7]);
}

// ---------------------------------------------------------------- masks -> line words + per-voxel mask byte + labels
__global__ __launch_bounds__(256) void k_masks(const float* __restrict__ x,
                                               const unsigned char* __restrict__ pocc,
                                               u64* __restrict__ lw_in,
                                               u64* __restrict__ lw_fin,
                                               unsigned char* __restrict__ m_in,
                                               float* __restrict__ labels) {
    int z = threadIdx.x;
    int y = blockIdx.x * 4 + threadIdx.y;
    int xx = blockIdx.y;
    int v = (xx * G + y) * G + z;
    int par = ((xx & 1) << 2) | ((y & 1) << 1) | (z & 1);
    const int gmap[8] = {0, 5, 4, 3, 4, 2, 1, 5};
    int g = gmap[par];
    int t = ((xx >> 1) + (y >> 1) + (z >> 1)) % 3;
    bool occ = pocc[(((xx >> 1) * S) + (y >> 1)) * S + (z >> 1)] != 0;
    bool ox = x[v] > 0.0f;
    bool g0 = (g == 0);

    bool mi[8], mf[8], lb[8];
    mi[0] = occ && g0 && (t == 0);
    mi[1] = (occ && g0 && (t == 1)) || (ox && g0 && (t == 0));
    mi[2] = (ox && g0 && (t < 2)) || (occ && g0 && (t == 2));
    mi[3] = (ox && g0)       || (occ && (g == 1));
    mi[4] = (ox && (g <= 1)) || (occ && (g == 2));
    mi[5] = (ox && (g <= 2)) || (occ && (g == 3));
    mi[6] = (ox && (g <= 3)) || (occ && (g == 4));
    mi[7] = (ox && (g <= 4)) || (occ && (g == 5));

    mf[0] = occ && g0 && (t == 0);
    mf[1] = occ && g0 && (t == 1);
    mf[2] = occ && g0 && (t == 2);
    mf[3] = occ && (g == 1);
    mf[4] = occ && (g == 2);
    mf[5] = occ && (g == 3);
    mf[6] = occ && (g == 4);
    mf[7] = occ && (g == 5);

    lb[0] = ox && g0 && (t == 0);
    lb[1] = ox && g0 && (t == 1);
    lb[2] = ox && g0 && (t == 2);
    lb[3] = ox && (g == 1);
    lb[4] = ox && (g == 2);
    lb[5] = ox && (g == 3);
    lb[6] = ox && (g == 4);
    lb[7] = ox && (g == 5);

    int line = xx * G + y;
    u32 mbyte = 0;
    #pragma unroll
    for (int c = 0; c < 8; ++c) {
        u64 wi = __ballot((int)mi[c]);
        u64 wf = __ballot((int)mf[c]);
        if (z == 0) {
            lw_in[c * 4096 + line] = wi;
            lw_fin[c * 4096 + line] = wf;
        }
        mbyte |= ((u32)mi[c]) << c;
        labels[(size_t)c * G3 + v] = lb[c] ? 1.0f : 0.0f;
    }
    m_in[v] = (unsigned char)mbyte;
}

// ---------------------------------------------------------------- pre-masked prob copies: mprob[ci] = probf16 * mask bit (b0+ci)
// one thread = one 8-u16 chunk; G3*16/8 = 524288 chunks = 2048 blocks x 256
__global__ __launch_bounds__(256) void k_maskprob(const u16* __restrict__ pf,
                                                  const unsigned char* __restrict__ m_in,
                                                  u16* __restrict__ mprob,
                                                  int b0, int nb) {
    int gid = blockIdx.x * 256 + threadIdx.x;
    size_t off = (size_t)gid * 8;
    uint4 d = *reinterpret_cast<const uint4*>(pf + off);
    unsigned char mb = m_in[gid >> 1];
    const uint4 z = make_uint4(0, 0, 0, 0);
    for (int ci = 0; ci < nb; ++ci) {
        int c = b0 + ci;
        uint4 o = ((mb >> c) & 1) ? d : z;
        *reinterpret_cast<uint4*>(mprob + (size_t)ci * G3 * 16 + off) = o;
    }
}

// ---------------------------------------------------------------- B-fragment prep (weights -> MFMA lane layout, bf16)
#define FRAGSTRIDE 38400   // u16 per coder (75 frags * 64 lanes * 8)
__global__ __launch_bounds__(64) void k_prep_bfrag(const float* __restrict__ wc1,
                                                   const float* __restrict__ wl1,
                                                   u16* __restrict__ bfrag) {
    int c = blockIdx.x;
    int frag = blockIdx.y;
    int lane = threadIdx.x;
    bool is5 = (c == 1 || c == 2);
    int R = is5 ? 2 : 1;
    int KS = 2 * R + 1;
    int npair = R + 1;
    int nfrag = KS * KS * npair;
    if (frag >= nfrag) return;
    const float* W = is5 ? (wl1 + (size_t)(c - 1) * 32000)
                         : (wc1 + (size_t)((c == 0) ? 0 : (c - 2)) * 6912);
    int dxdy = frag / npair, p = frag - dxdy * npair;
    int dziA = 2 * p;
    int co = lane & 15, kg = lane >> 4;
    u16 outv[8];
    #pragma unroll
    for (int j = 0; j < 8; ++j) {
        int k = kg * 8 + j;
        int ci = k & 15;
        int dzi = (k < 16) ? dziA : (dziA + 1);
        float v = 0.0f;
        if (dzi < KS)
            v = W[(size_t)(dxdy * KS + dzi) * 256 + ci * 16 + co];
        outv[j] = (u16)f2bf_rne(v);
    }
    u16* o = bfrag + (size_t)c * FRAGSTRIDE + ((size_t)frag * 64 + lane) * 8;
    uint4 pk;
    pk.x = outv[0] | ((u32)outv[1] << 16);
    pk.y = outv[2] | ((u32)outv[3] << 16);
    pk.z = outv[4] | ((u32)outv[5] << 16);
    pk.w = outv[6] | ((u32)outv[7] << 16);
    *reinterpret_cast<uint4*>(o) = pk;
}

// ---------------------------------------------------------------- conv1 via MFMA (r11 compute + global_load_lds staging)
// LDS slot (y-line): 72 voxel slots (4 front pad, 64 data, 4 back pad), stride 2304B.
// voxel lz, half h -> byte = s*2304 + lz*32 + ((h ^ ((lz>>2)&1))*16). Pads zeroed once.
// Staging: mprob pre-masked, so live lines stage all 64 voxels with 2 gload16 per line;
// src per-lane offset = inverse swizzle: (lane>>1)*32 + ((lane&1)^((lane>>3)&1)^1)*16.
__global__ __launch_bounds__(256) void k_conv1_mfma(const u16* __restrict__ mprob,
                                                    const u64* __restrict__ lw_in,
                                                    const u16* __restrict__ bfrag,
                                                    const float* __restrict__ bc1,
                                                    const float* __restrict__ bl1,
                                                    u16* __restrict__ hbase,
                                                    int b0) {
    int ci = blockIdx.y;
    int c = b0 + ci;
    bool is5 = (c == 1 || c == 2);
    int R = is5 ? 2 : 1;
    int KS = 2 * R + 1, npair = R + 1;
    const u64* lw = lw_in + (size_t)c * 4096;
    u16* h_c = hbase + (size_t)ci * G3 * 16;
    const u16* mp = mprob + (size_t)ci * G3 * 16;
    const u16* bf = bfrag + (size_t)c * FRAGSTRIDE;
    const float* bptr = is5 ? (bl1 + (c - 1) * 16)
                            : (bc1 + ((c == 0) ? 0 : (c - 2)) * 16);

    int x = blockIdx.x >> 4;
    int y0 = (blockIdx.x & 15) << 2;
    int w = threadIdx.y;
    int lane = threadIdx.x;
    int yw = y0 + w;

    u64 w0 = rfl64(lw[x * G + yw]);
    u64 anyw = lw[x * G + y0] | lw[x * G + y0 + 1] | lw[x * G + y0 + 2] | lw[x * G + y0 + 3];
    if (anyw == 0ULL) return;          // uniform across WG: safe early-out (before barriers)

    __shared__ u32 lds[8 * 2304 / 4];  // 18432 B
    char* ldsc = reinterpret_cast<char*>(lds);

    int col = lane & 15, kg = lane >> 4;
    float bv = bptr[col];
    f32x4 acc[4];
    #pragma unroll
    for (int s = 0; s < 4; ++s) acc[s] = (f32x4){bv, bv, bv, bv};

    // one-time pad zeroing (pads are dx-invariant; gload never touches them)
    int t = w * 64 + lane;
    if (t < 128) {
        int slot = t >> 4, q = t & 15;
        int off = (q < 8) ? (q * 16) : (2176 + (q - 8) * 16);
        *reinterpret_cast<uint4*>(ldsc + slot * 2304 + off) = make_uint4(0, 0, 0, 0);
    }

    // per-lane staging source offset (inverse of the read-side XOR-half swizzle)
    u32 goff = ((u32)lane >> 1) * 32 +
               ((((u32)lane & 1) ^ (((u32)lane >> 3) & 1) ^ 1u) * 16);

    int nlines = 4 + 2 * R;

    for (int dx = -R; dx <= R; ++dx) {
        int nx = x + dx;
        __syncthreads();
        if ((unsigned)nx < G) {
            for (int s = w; s < nlines; s += 4) {
                int ny = y0 - R + s;
                if ((unsigned)ny >= G) continue;
                if (lw[nx * G + ny] == 0ULL) continue;   // dead line: stale LDS never read
                const char* src = reinterpret_cast<const char*>(mp + (size_t)(nx * G + ny) * 1024) + goff;
                char* dst = ldsc + s * 2304 + 128;
                gload16(src, dst);
                gload16(src + 1024, dst + 1024);
            }
        }
        __syncthreads();
        if (w0 == 0ULL || (unsigned)nx >= G) continue;

        for (int dy = -R; dy <= R; ++dy) {
            int ny = yw + dy;
            if ((unsigned)ny >= G) continue;
            u64 wn = rfl64(lw[nx * G + ny]);
            if (wn == 0ULL) continue;
            int slot = w + dy + R;
            for (int p = 0; p < npair; ++p) {
                int dzA = -R + 2 * p;
                int dzB = dzA + 1;
                bool hasB = (dzB <= R);
                u64 hit = tap_hit(w0, wn, dzA);
                if (hasB) hit |= tap_hit(w0, wn, dzB);
                if (hit == 0ULL) continue;
                int frag = ((dx + R) * KS + (dy + R)) * npair + p;
                s16x8 bf8 = *reinterpret_cast<const s16x8*>(bf + ((size_t)frag * 64 + lane) * 8);
                int dz = (kg < 2) ? dzA : (hasB ? dzB : dzA);
                int lzb = col + dz + 4;
                const char* ab = ldsc + slot * 2304 + lzb * 32
                                 + (((kg & 1) ^ ((lzb >> 2) & 1)) * 16);
                #pragma unroll
                for (int s = 0; s < 4; ++s) {
                    if (((hit >> (s * 16)) & 0xFFFFULL) == 0ULL) continue;
                    s16x8 a = *reinterpret_cast<const s16x8*>(ab + s * 512);
                    acc[s] = __builtin_amdgcn_mfma_f32_16x16x32_bf16(a, bf8, acc[s], 0, 0, 0);
                }
            }
        }
    }

    if (w0 == 0ULL) return;
    u16* hline = h_c + (size_t)(x * G + yw) * G * 16;
    #pragma unroll
    for (int s = 0; s < 4; ++s) {
        #pragma unroll
        for (int r = 0; r < 4; ++r) {
            int z = s * 16 + kg * 4 + r;
            if ((w0 >> z) & 1) {
                float v = fmaxf(acc[s][r], 0.0f);
                hline[z * 16 + col] = (u16)f2bf_rne(v);
            }
        }
    }
}

// ---------------------------------------------------------------- coder conv2 body (C->1, K^3, sigmoid) + ILP acc split
template <int KS>
__device__ __forceinline__ void conv2_body(const u32* __restrict__ h_c,
                                           const u64* __restrict__ lwi,
                                           const u64* __restrict__ lwf,
                                           const float* __restrict__ w2,
                                           const float* __restrict__ b2,
                                           float* __restrict__ outp) {
    const int R = KS / 2;
    int z = threadIdx.x;
    int line = blockIdx.x * 4 + threadIdx.y;
    int xx = line >> 6, y = line & 63;
    int v = (xx * G + y) * G + z;
    u64 wf = rfl64(lwf[line]);
    if (wf == 0ULL) { outp[v] = 0.0f; return; }
    bool m = (wf >> z) & 1;

    float ac0 = 0.0f, ac1 = 0.0f;
    for (int dx = -R; dx <= R; ++dx) {
        int nx = xx + dx; if ((unsigned)nx >= G) continue;
        for (int dy = -R; dy <= R; ++dy) {
            int ny = y + dy; if ((unsigned)ny >= G) continue;
            u64 wn = rfl64(lwi[nx * G + ny]);
            if (wn == 0ULL) continue;
            const float* wbase = w2 + (size_t)(((dx + R) * KS + (dy + R)) * KS) * 16;
            #pragma unroll
            for (int dz = -R; dz <= R; ++dz) {
                if (tap_hit(wf, wn, dz) == 0ULL) continue;
                int nz = z + dz;
                bool ok = (unsigned)nz < G;
                int nzc = ok ? nz : 0;
                bool mn = ok && ((wn >> nzc) & 1);
                const float* w = wbase + (dz + R) * 16;
                if (mn) {
                    const uint4* h4 = reinterpret_cast<const uint4*>(
                        h_c + ((size_t)((nx * G + ny) * G + nzc)) * 8);
                    uint4 Ua = h4[0], Ub = h4[1];
                    u32 uu[8] = {Ua.x, Ua.y, Ua.z, Ua.w, Ub.x, Ub.y, Ub.z, Ub.w};
                    float s0 = 0.0f, s1 = 0.0f;
                    #pragma unroll
                    for (int i = 0; i < 8; ++i) {
                        float lo = __uint_as_float(uu[i] << 16);
                        float hi = __uint_as_float(uu[i] & 0xffff0000u);
                        s0 = fmaf(lo, w[2 * i], s0);
                        s1 = fmaf(hi, w[2 * i + 1], s1);
                    }
                    if (((dz + R) & 1) == 0) ac0 += s0 + s1;
                    else                     ac1 += s0 + s1;
                }
            }
        }
    }
    float acc = b2[0] + ac0 + ac1;
    outp[v] = m ? sigmoidf_(acc) : 0.0f;
}

__global__ __launch_bounds__(256) void k_conv2_all(const u32* __restrict__ hbase,
                                                   const u64* __restrict__ lw_in,
                                                   const u64* __restrict__ lw_fin,
                                                   const float* __restrict__ wc2,
                                                   const float* __restrict__ bc2,
                                                   const float* __restrict__ wl2,
                                                   const float* __restrict__ bl2,
                                                   float* __restrict__ out,
                                                   int b0) {
    int ci = blockIdx.y;
    int c = b0 + ci;
    const u64* lwi = lw_in + (size_t)c * 4096;
    const u64* lwf = lw_fin + (size_t)c * 4096;
    const u32* h_c = hbase + (size_t)ci * G3 * 8;
    float* outp = out + (size_t)c * G3;
    if (c == 1 || c == 2) {
        conv2_body<5>(h_c, lwi, lwf, wl2 + (size_t)(c - 1) * 2000, bl2 + (c - 1), outp);
    } else {
        int j = (c == 0) ? 0 : (c - 2);
        conv2_body<3>(h_c, lwi, lwf, wc2 + (size_t)j * 432, bc2 + j, outp);
    }
}

// ---------------------------------------------------------------- launch
extern "C" void kernel_launch(void* const* d_in, const int* in_sizes, int n_in,
                              void* d_out, int out_size, void* d_ws, size_t ws_size,
                              hipStream_t stream) {
    const float* x      = (const float*)d_in[0];
    const float* w_fel1 = (const float*)d_in[3];
    const float* b_fel1 = (const float*)d_in[4];
    const float* w_fel2 = (const float*)d_in[5];
    const float* b_fel2 = (const float*)d_in[6];
    const float* w_up   = (const float*)d_in[7];
    const float* b_up   = (const float*)d_in[8];
    const float* wc1    = (const float*)d_in[9];
    const float* bc1    = (const float*)d_in[10];
    const float* wc2    = (const float*)d_in[11];
    const float* bc2    = (const float*)d_in[12];
    const float* wl1    = (const float*)d_in[13];
    const float* bl1    = (const float*)d_in[14];
    const float* wl2    = (const float*)d_in[15];
    const float* bl2    = (const float*)d_in[16];
    float* out = (float*)d_out;

    char* ws = (char*)d_ws;
    u16*  probf16 = (u16*)(ws);                            // 8 MB  bf16[4096 lines][64][16]
    float* h1     = (float*)(ws + 8388608);                // 2 MB (dead after k_fel2)
    float* h2     = (float*)(ws + 10485760);               // 2 MB
    unsigned char* pocc = (unsigned char*)(ws + 12582912); // 32 KB
    u64* lw_in  = (u64*)(ws + 12615680);                   // 256 KB
    u64* lw_fin = (u64*)(ws + 12877824);                   // 256 KB
    u16* bfrag  = (u16*)(ws + 13139968);                   // 600 KB (ends 13754368)
    unsigned char* m_in = (unsigned char*)(ws + 8388608);  // 256 KB, ALIASES h1 (written after h1 dead)
    u16* mprob  = (u16*)(ws + 13754368);                   // NB * 8 MB
    // hbase follows mprob: NB * 8 MB
    // NB=4 footprint: 13754368 + 64 MB = 80,863,232 B — EXACTLY the r7/r11-proven extent

    int NB = 4;
    if (13754368 + (size_t)16 * 8388608 <= ws_size) NB = 8;   // 148 MB variant if workspace allows
    u16* hbase = (u16*)(ws + 13754368 + (size_t)NB * 8388608);

    k_pocc <<<dim3(S3 / 256), dim3(256), 0, stream>>>(x, pocc);
    k_fel1 <<<dim3(S3 * 16 / 256), dim3(256), 0, stream>>>(pocc, w_fel1, b_fel1, h1);
    k_fel2 <<<dim3(S3 * 16 / 256), dim3(256), 0, stream>>>(pocc, h1, w_fel2, b_fel2, h2);
    k_up   <<<dim3(S3 * 8 / 256), dim3(256), 0, stream>>>(pocc, h2, w_up, b_up, probf16);
    k_masks<<<dim3(16, 64), dim3(64, 4), 0, stream>>>(x, pocc, lw_in, lw_fin, m_in,
                                                      out + (size_t)8 * G3);
    k_prep_bfrag<<<dim3(8, 75), dim3(64), 0, stream>>>(wc1, wl1, bfrag);

    for (int b0 = 0; b0 < 8; b0 += NB) {
        int nb = (8 - b0 < NB) ? (8 - b0) : NB;
        k_maskprob<<<dim3(G3 * 16 / 8 / 256), dim3(256), 0, stream>>>(probf16, m_in, mprob, b0, nb);
        k_conv1_mfma<<<dim3(1024, nb), dim3(64, 4), 0, stream>>>(
            mprob, lw_in, bfrag, bc1, bl1, hbase, b0);
        k_conv2_all<<<dim3(1024, nb), dim3(64, 4), 0, stream>>>(
            (const u32*)hbase, lw_in, lw_fin, wc2, bc2, wl2, bl2, out, b0);
    }
}

// Round 14
// 209.850 us; speedup vs baseline: 1.0242x; 1.0050x over previous
//
#include <hip/hip_runtime.h>
#include <cstdint>
#include <math.h>

#define G 64
#define S 32
#define G3 (G*G*G)
#define S3 (S*S*S)

typedef unsigned long long u64;
typedef unsigned int u32;
typedef unsigned short u16;

typedef __attribute__((ext_vector_type(8))) short s16x8;   // 8 bf16 (4 VGPRs)
typedef __attribute__((ext_vector_type(4))) float f32x4;   // MFMA acc

__device__ __forceinline__ float sigmoidf_(float v) {
    return 1.0f / (1.0f + expf(-v));
}
__device__ __forceinline__ u32 f2bf_rne(float f) {   // round-to-nearest-even bf16
    u32 u = __float_as_uint(f);
    u += 0x7fff + ((u >> 16) & 1);
    return u >> 16;
}
__device__ __forceinline__ u64 rfl64(u64 v) {
    u32 lo = __builtin_amdgcn_readfirstlane((u32)v);
    u32 hi = __builtin_amdgcn_readfirstlane((u32)(v >> 32));
    return ((u64)hi << 32) | lo;
}
__device__ __forceinline__ u64 tap_hit(u64 wout, u64 wn, int dz) {
    return (dz >= 0) ? (wout & (wn >> dz)) : (wout & (wn << (-dz)));
}
// async global->LDS, 16B per lane; dest = base + lane*16 (wave-uniform base)
__device__ __forceinline__ void gload16(const void* g, void* l) {
    __builtin_amdgcn_global_load_lds(
        (const __attribute__((address_space(1))) unsigned int*)g,
        (__attribute__((address_space(3))) unsigned int*)l, 16, 0, 0);
}

// ---------------------------------------------------------------- parent occupancy
__global__ __launch_bounds__(256) void k_pocc(const float* __restrict__ x,
                                              unsigned char* __restrict__ pocc) {
    int p = blockIdx.x * 256 + threadIdx.x;
    if (p >= S3) return;
    int pz = p & 31, py = (p >> 5) & 31, px = p >> 10;
    const float* b = x + (((size_t)(px * 2) * G + py * 2) * G + pz * 2);
    bool occ = false;
    #pragma unroll
    for (int a = 0; a < 2; a++)
        #pragma unroll
        for (int bb = 0; bb < 2; bb++)
            #pragma unroll
            for (int c = 0; c < 2; c++)
                occ = occ || (b[((size_t)a * G + bb) * G + c] > 0.0f);
    pocc[p] = occ ? 1 : 0;
}

// ---------------------------------------------------------------- FEL conv1: 1->16, 3^3, relu  (thread = (p, co))
__global__ __launch_bounds__(256) void k_fel1(const unsigned char* __restrict__ pocc,
                                              const float* __restrict__ w1,
                                              const float* __restrict__ b1,
                                              float* __restrict__ h1) {
    int idx = blockIdx.x * 256 + threadIdx.x;       // S3*16
    int p = idx >> 4, co = idx & 15;
    int pz = p & 31, py = (p >> 5) & 31, px = p >> 10;
    if (!pocc[p]) { h1[idx] = 0.0f; return; }
    float a = b1[co];
    for (int dx = -1; dx <= 1; ++dx) {
        int nx = px + dx; if ((unsigned)nx >= S) continue;
        for (int dy = -1; dy <= 1; ++dy) {
            int ny = py + dy; if ((unsigned)ny >= S) continue;
            for (int dz = -1; dz <= 1; ++dz) {
                int nz = pz + dz; if ((unsigned)nz >= S) continue;
                if (pocc[(nx * S + ny) * S + nz])
                    a += w1[(((dx + 1) * 3 + (dy + 1)) * 3 + (dz + 1)) * 16 + co];
            }
        }
    }
    h1[idx] = fmaxf(a, 0.0f);
}

// ---------------------------------------------------------------- FEL conv2: 16->16, 3^3  (thread = (p, co))
__global__ __launch_bounds__(256) void k_fel2(const unsigned char* __restrict__ pocc,
                                              const float* __restrict__ h1,
                                              const float* __restrict__ w2,
                                              const float* __restrict__ b2,
                                              float* __restrict__ h2) {
    int idx = blockIdx.x * 256 + threadIdx.x;       // S3*16
    int p = idx >> 4, co = idx & 15;
    int pz = p & 31, py = (p >> 5) & 31, px = p >> 10;
    if (!pocc[p]) { h2[idx] = 0.0f; return; }
    float a = b2[co];
    for (int dx = -1; dx <= 1; ++dx) {
        int nx = px + dx; if ((unsigned)nx >= S) continue;
        for (int dy = -1; dy <= 1; ++dy) {
            int ny = py + dy; if ((unsigned)ny >= S) continue;
            for (int dz = -1; dz <= 1; ++dz) {
                int nz = pz + dz; if ((unsigned)nz >= S) continue;
                const float* f = h1 + (size_t)((nx * S + ny) * S + nz) * 16;
                const float* ww = w2 + (size_t)(((dx + 1) * 3 + (dy + 1)) * 3 + (dz + 1)) * 256 + co;
                #pragma unroll
                for (int ci = 0; ci < 16; ++ci)
                    a = fmaf(f[ci], ww[ci * 16], a);
            }
        }
    }
    h2[idx] = a;
}

// ---------------------------------------------------------------- generative up (k2 s2) -> prob_f (bf16, [line][64][16])  (thread = (p, o))
__global__ __launch_bounds__(256) void k_up(const unsigned char* __restrict__ pocc,
                                            const float* __restrict__ h2,
                                            const float* __restrict__ wup,
                                            const float* __restrict__ bup,
                                            u16* __restrict__ pf) {
    int idx = blockIdx.x * 256 + threadIdx.x;       // S3*8
    int p = idx >> 3, o = idx & 7;
    int pz = p & 31, py = (p >> 5) & 31, px = p >> 10;
    bool occ = pocc[p] != 0;
    int a = o >> 2, b = (o >> 1) & 1, c = o & 1;
    int line = (2 * px + a) * G + (2 * py + b);
    u16* op = pf + ((size_t)line * 64 + (2 * pz + c)) * 16;
    uint4* o4 = reinterpret_cast<uint4*>(op);
    if (!occ) {
        o4[0] = make_uint4(0, 0, 0, 0);
        o4[1] = make_uint4(0, 0, 0, 0);
        return;
    }
    float h[16];
    const float* hp = h2 + (size_t)p * 16;
    #pragma unroll
    for (int i = 0; i < 16; i++) h[i] = hp[i];
    u32 pk[8];
    #pragma unroll
    for (int i = 0; i < 8; ++i) {
        float a0 = bup[2 * i], a1 = bup[2 * i + 1];
        #pragma unroll
        for (int cc = 0; cc < 16; cc++) {
            a0 = fmaf(h[cc], wup[(o * 16 + cc) * 16 + 2 * i], a0);
            a1 = fmaf(h[cc], wup[(o * 16 + cc) * 16 + 2 * i + 1], a1);
        }
        pk[i] = f2bf_rne(a0) | (f2bf_rne(a1) << 16);
    }
    o4[0] = make_uint4(pk[0], pk[1], pk[2], pk[3]);
    o4[1] = make_uint4(pk[4], pk[5], pk[6], pk[7]);
}

// ---------------------------------------------------------------- masks -> 64-bit line words + labels
__global__ __launch_bounds__(256) void k_masks(const float* __restrict__ x,
                                               const unsigned char* __restrict__ pocc,
                                               u64* __restrict__ lw_in,
                                               u64* __restrict__ lw_fin,
                                               float* __restrict__ labels) {
    int z = threadIdx.x;
    int y = blockIdx.x * 4 + threadIdx.y;
    int xx = blockIdx.y;
    int v = (xx * G + y) * G + z;
    int par = ((xx & 1) << 2) | ((y & 1) << 1) | (z & 1);
    const int gmap[8] = {0, 5, 4, 3, 4, 2, 1, 5};
    int g = gmap[par];
    int t = ((xx >> 1) + (y >> 1) + (z >> 1)) % 3;
    bool occ = pocc[(((xx >> 1) * S) + (y >> 1)) * S + (z >> 1)] != 0;
    bool ox = x[v] > 0.0f;
    bool g0 = (g == 0);

    bool mi[8], mf[8], lb[8];
    mi[0] = occ && g0 && (t == 0);
    mi[1] = (occ && g0 && (t == 1)) || (ox && g0 && (t == 0));
    mi[2] = (ox && g0 && (t < 2)) || (occ && g0 && (t == 2));
    mi[3] = (ox && g0)       || (occ && (g == 1));
    mi[4] = (ox && (g <= 1)) || (occ && (g == 2));
    mi[5] = (ox && (g <= 2)) || (occ && (g == 3));
    mi[6] = (ox && (g <= 3)) || (occ && (g == 4));
    mi[7] = (ox && (g <= 4)) || (occ && (g == 5));

    mf[0] = occ && g0 && (t == 0);
    mf[1] = occ && g0 && (t == 1);
    mf[2] = occ && g0 && (t == 2);
    mf[3] = occ && (g == 1);
    mf[4] = occ && (g == 2);
    mf[5] = occ && (g == 3);
    mf[6] = occ && (g == 4);
    mf[7] = occ && (g == 5);

    lb[0] = ox && g0 && (t == 0);
    lb[1] = ox && g0 && (t == 1);
    lb[2] = ox && g0 && (t == 2);
    lb[3] = ox && (g == 1);
    lb[4] = ox && (g == 2);
    lb[5] = ox && (g == 3);
    lb[6] = ox && (g == 4);
    lb[7] = ox && (g == 5);

    int line = xx * G + y;
    #pragma unroll
    for (int c = 0; c < 8; ++c) {
        u64 wi = __ballot((int)mi[c]);
        u64 wf = __ballot((int)mf[c]);
        if (z == 0) {
            lw_in[c * 4096 + line] = wi;
            lw_fin[c * 4096 + line] = wf;
        }
        labels[(size_t)c * G3 + v] = lb[c] ? 1.0f : 0.0f;
    }
}

// ---------------------------------------------------------------- B-fragment prep (weights -> MFMA lane layout, bf16)
#define FRAGSTRIDE 38400   // u16 per coder (75 frags * 64 lanes * 8)
__global__ __launch_bounds__(64) void k_prep_bfrag(const float* __restrict__ wc1,
                                                   const float* __restrict__ wl1,
                                                   u16* __restrict__ bfrag) {
    int c = blockIdx.x;
    int frag = blockIdx.y;
    int lane = threadIdx.x;
    bool is5 = (c == 1 || c == 2);
    int R = is5 ? 2 : 1;
    int KS = 2 * R + 1;
    int npair = R + 1;
    int nfrag = KS * KS * npair;
    if (frag >= nfrag) return;
    const float* W = is5 ? (wl1 + (size_t)(c - 1) * 32000)
                         : (wc1 + (size_t)((c == 0) ? 0 : (c - 2)) * 6912);
    int dxdy = frag / npair, p = frag - dxdy * npair;
    int dziA = 2 * p;
    int co = lane & 15, kg = lane >> 4;
    u16 outv[8];
    #pragma unroll
    for (int j = 0; j < 8; ++j) {
        int k = kg * 8 + j;
        int ci = k & 15;
        int dzi = (k < 16) ? dziA : (dziA + 1);
        float v = 0.0f;
        if (dzi < KS)
            v = W[(size_t)(dxdy * KS + dzi) * 256 + ci * 16 + co];
        outv[j] = (u16)f2bf_rne(v);
    }
    u16* o = bfrag + (size_t)c * FRAGSTRIDE + ((size_t)frag * 64 + lane) * 8;
    uint4 pk;
    pk.x = outv[0] | ((u32)outv[1] << 16);
    pk.y = outv[2] | ((u32)outv[3] << 16);
    pk.z = outv[4] | ((u32)outv[5] << 16);
    pk.w = outv[6] | ((u32)outv[7] << 16);
    *reinterpret_cast<uint4*>(o) = pk;
}

// ---------------------------------------------------------------- conv1 via MFMA: gload staging from SHARED probf16 + in-LDS mask pass
// LDS slot (y-line): 72 voxel slots (4 front pad, 64 data, 4 back pad), stride 2304B.
// voxel lz, half h -> byte = s*2304 + lz*32 + ((h ^ ((lz>>2)&1))*16). Pads zeroed once.
// Staging: 2 gload16 per live line (src XOR-permuted, dest linear) from shared probf16;
// then each wave waits its own vmcnt and zeroes masked-off voxels of its own slots.
__global__ __launch_bounds__(256) void k_conv1_mfma(const u16* __restrict__ pf,
                                                    const u64* __restrict__ lw_in,
                                                    const u16* __restrict__ bfrag,
                                                    const float* __restrict__ bc1,
                                                    const float* __restrict__ bl1,
                                                    u16* __restrict__ hbase) {
    int c = blockIdx.y;
    bool is5 = (c == 1 || c == 2);
    int R = is5 ? 2 : 1;
    int KS = 2 * R + 1, npair = R + 1;
    const u64* lw = lw_in + (size_t)c * 4096;
    u16* h_c = hbase + (size_t)c * G3 * 16;
    const u16* bf = bfrag + (size_t)c * FRAGSTRIDE;
    const float* bptr = is5 ? (bl1 + (c - 1) * 16)
                            : (bc1 + ((c == 0) ? 0 : (c - 2)) * 16);

    int x = blockIdx.x >> 4;
    int y0 = (blockIdx.x & 15) << 2;
    int w = threadIdx.y;
    int lane = threadIdx.x;
    int yw = y0 + w;

    u64 w0 = rfl64(lw[x * G + yw]);
    u64 anyw = lw[x * G + y0] | lw[x * G + y0 + 1] | lw[x * G + y0 + 2] | lw[x * G + y0 + 3];
    if (anyw == 0ULL) return;          // uniform across WG: safe early-out (before barriers)

    __shared__ u32 lds[8 * 2304 / 4];  // 18432 B
    char* ldsc = reinterpret_cast<char*>(lds);

    int col = lane & 15, kg = lane >> 4;
    float bv = bptr[col];
    f32x4 acc[4];
    #pragma unroll
    for (int s = 0; s < 4; ++s) acc[s] = (f32x4){bv, bv, bv, bv};

    // one-time pad zeroing (pads are dx-invariant; gload never touches them)
    int t = w * 64 + lane;
    if (t < 128) {
        int slot = t >> 4, q = t & 15;
        int off = (q < 8) ? (q * 16) : (2176 + (q - 8) * 16);
        *reinterpret_cast<uint4*>(ldsc + slot * 2304 + off) = make_uint4(0, 0, 0, 0);
    }

    // per-lane staging source offset (inverse of the read-side XOR-half swizzle)
    u32 goff = ((u32)lane >> 1) * 32 +
               ((((u32)lane & 1) ^ (((u32)lane >> 3) & 1) ^ 1u) * 16);

    int nlines = 4 + 2 * R;

    for (int dx = -R; dx <= R; ++dx) {
        int nx = x + dx;
        __syncthreads();                       // prev compute done before overwrite
        if ((unsigned)nx < G) {
            // issue gloads for this wave's slots (live lines only)
            for (int s = w; s < nlines; s += 4) {
                int ny = y0 - R + s;
                u64 wn = ((unsigned)ny < G) ? lw[nx * G + ny] : 0ULL;
                if (wn != 0ULL) {
                    const char* src = reinterpret_cast<const char*>(
                        pf + (size_t)(nx * G + ny) * 1024) + goff;
                    char* dst = ldsc + s * 2304 + 128;
                    gload16(src, dst);
                    gload16(src + 1024, dst + 1024);
                }
            }
            // wait own gloads, then zero masked-off voxels of own slots
            asm volatile("s_waitcnt vmcnt(0)" ::: "memory");
            for (int s = w; s < nlines; s += 4) {
                int ny = y0 - R + s;
                u64 wn = ((unsigned)ny < G) ? lw[nx * G + ny] : 0ULL;
                bool live = (wn >> lane) & 1;  // lane = voxel z within the line
                if (!live) {
                    char* d = ldsc + s * 2304 + (lane + 4) * 32;
                    *reinterpret_cast<uint4*>(d) = make_uint4(0, 0, 0, 0);
                    *reinterpret_cast<uint4*>(d + 16) = make_uint4(0, 0, 0, 0);
                }
            }
        }
        __syncthreads();                       // staged+masked data visible to all waves
        if (w0 == 0ULL || (unsigned)nx >= G) continue;

        for (int dy = -R; dy <= R; ++dy) {
            int ny = yw + dy;
            if ((unsigned)ny >= G) continue;
            u64 wn = rfl64(lw[nx * G + ny]);
            if (wn == 0ULL) continue;
            int slot = w + dy + R;
            for (int p = 0; p < npair; ++p) {
                int dzA = -R + 2 * p;
                int dzB = dzA + 1;
                bool hasB = (dzB <= R);
                u64 hit = tap_hit(w0, wn, dzA);
                if (hasB) hit |= tap_hit(w0, wn, dzB);
                if (hit == 0ULL) continue;
                int frag = ((dx + R) * KS + (dy + R)) * npair + p;
                s16x8 bf8 = *reinterpret_cast<const s16x8*>(bf + ((size_t)frag * 64 + lane) * 8);
                int dz = (kg < 2) ? dzA : (hasB ? dzB : dzA);
                int lzb = col + dz + 4;
                const char* ab = ldsc + slot * 2304 + lzb * 32
                                 + (((kg & 1) ^ ((lzb >> 2) & 1)) * 16);
                #pragma unroll
                for (int s = 0; s < 4; ++s) {
                    if (((hit >> (s * 16)) & 0xFFFFULL) == 0ULL) continue;
                    s16x8 a = *reinterpret_cast<const s16x8*>(ab + s * 512);
                    acc[s] = __builtin_amdgcn_mfma_f32_16x16x32_bf16(a, bf8, acc[s], 0, 0, 0);
                }
            }
        }
    }

    if (w0 == 0ULL) return;
    u16* hline = h_c + (size_t)(x * G + yw) * G * 16;
    #pragma unroll
    for (int s = 0; s < 4; ++s) {
        #pragma unroll
        for (int r = 0; r < 4; ++r) {
            int z = s * 16 + kg * 4 + r;
            if ((w0 >> z) & 1) {
                float v = fmaxf(acc[s][r], 0.0f);
                hline[z * 16 + col] = (u16)f2bf_rne(v);
            }
        }
    }
}

// ---------------------------------------------------------------- coder conv2 body (C->1, K^3, sigmoid) + ILP acc split
template <int KS>
__device__ __forceinline__ void conv2_body(const u32* __restrict__ h_c,
                                           const u64* __restrict__ lwi,
                                           const u64* __restrict__ lwf,
                                           const float* __restrict__ w2,
                                           const float* __restrict__ b2,
                                           float* __restrict__ outp) {
    const int R = KS / 2;
    int z = threadIdx.x;
    int line = blockIdx.x * 4 + threadIdx.y;
    int xx = line >> 6, y = line & 63;
    int v = (xx * G + y) * G + z;
    u64 wf = rfl64(lwf[line]);
    if (wf == 0ULL) { outp[v] = 0.0f; return; }
    bool m = (wf >> z) & 1;

    float ac0 = 0.0f, ac1 = 0.0f;
    for (int dx = -R; dx <= R; ++dx) {
        int nx = xx + dx; if ((unsigned)nx >= G) continue;
        for (int dy = -R; dy <= R; ++dy) {
            int ny = y + dy; if ((unsigned)ny >= G) continue;
            u64 wn = rfl64(lwi[nx * G + ny]);
            if (wn == 0ULL) continue;
            const float* wbase = w2 + (size_t)(((dx + R) * KS + (dy + R)) * KS) * 16;
            #pragma unroll
            for (int dz = -R; dz <= R; ++dz) {
                if (tap_hit(wf, wn, dz) == 0ULL) continue;
                int nz = z + dz;
                bool ok = (unsigned)nz < G;
                int nzc = ok ? nz : 0;
                bool mn = ok && ((wn >> nzc) & 1);
                const float* w = wbase + (dz + R) * 16;
                if (mn) {
                    const uint4* h4 = reinterpret_cast<const uint4*>(
                        h_c + ((size_t)((nx * G + ny) * G + nzc)) * 8);
                    uint4 Ua = h4[0], Ub = h4[1];
                    u32 uu[8] = {Ua.x, Ua.y, Ua.z, Ua.w, Ub.x, Ub.y, Ub.z, Ub.w};
                    float s0 = 0.0f, s1 = 0.0f;
                    #pragma unroll
                    for (int i = 0; i < 8; ++i) {
                        float lo = __uint_as_float(uu[i] << 16);
                        float hi = __uint_as_float(uu[i] & 0xffff0000u);
                        s0 = fmaf(lo, w[2 * i], s0);
                        s1 = fmaf(hi, w[2 * i + 1], s1);
                    }
                    if (((dz + R) & 1) == 0) ac0 += s0 + s1;
                    else                     ac1 += s0 + s1;
                }
            }
        }
    }
    float acc = b2[0] + ac0 + ac1;
    outp[v] = m ? sigmoidf_(acc) : 0.0f;
}

__global__ __launch_bounds__(256) void k_conv2_all(const u32* __restrict__ hbase,
                                                   const u64* __restrict__ lw_in,
                                                   const u64* __restrict__ lw_fin,
                                                   const float* __restrict__ wc2,
                                                   const float* __restrict__ bc2,
                                                   const float* __restrict__ wl2,
                                                   const float* __restrict__ bl2,
                                                   float* __restrict__ out) {
    int c = blockIdx.y;
    const u64* lwi = lw_in + (size_t)c * 4096;
    const u64* lwf = lw_fin + (size_t)c * 4096;
    const u32* h_c = hbase + (size_t)c * G3 * 8;
    float* outp = out + (size_t)c * G3;
    if (c == 1 || c == 2) {
        conv2_body<5>(h_c, lwi, lwf, wl2 + (size_t)(c - 1) * 2000, bl2 + (c - 1), outp);
    } else {
        int j = (c == 0) ? 0 : (c - 2);
        conv2_body<3>(h_c, lwi, lwf, wc2 + (size_t)j * 432, bc2 + j, outp);
    }
}

// ---------------------------------------------------------------- launch
extern "C" void kernel_launch(void* const* d_in, const int* in_sizes, int n_in,
                              void* d_out, int out_size, void* d_ws, size_t ws_size,
                              hipStream_t stream) {
    const float* x      = (const float*)d_in[0];
    const float* w_fel1 = (const float*)d_in[3];
    const float* b_fel1 = (const float*)d_in[4];
    const float* w_fel2 = (const float*)d_in[5];
    const float* b_fel2 = (const float*)d_in[6];
    const float* w_up   = (const float*)d_in[7];
    const float* b_up   = (const float*)d_in[8];
    const float* wc1    = (const float*)d_in[9];
    const float* bc1    = (const float*)d_in[10];
    const float* wc2    = (const float*)d_in[11];
    const float* bc2    = (const float*)d_in[12];
    const float* wl1    = (const float*)d_in[13];
    const float* bl1    = (const float*)d_in[14];
    const float* wl2    = (const float*)d_in[15];
    const float* bl2    = (const float*)d_in[16];
    float* out = (float*)d_out;

    char* ws = (char*)d_ws;
    u16*  probf16 = (u16*)(ws);                            // 8 MB  bf16[4096 lines][64][16]
    float* h1     = (float*)(ws + 8388608);                // 2 MB
    float* h2     = (float*)(ws + 10485760);               // 2 MB
    unsigned char* pocc = (unsigned char*)(ws + 12582912); // 32 KB
    u64* lw_in  = (u64*)(ws + 12615680);                   // 256 KB
    u64* lw_fin = (u64*)(ws + 12877824);                   // 256 KB
    u16* bfrag  = (u16*)(ws + 13139968);                   // 600 KB (ends 13754368)
    u16* hbase  = (u16*)(ws + 13754368);                   // 64 MB (8 coders x 8 MB bf16 h)
    // footprint 80,863,232 B — EXACTLY the r7/r11/r13-proven extent

    k_pocc <<<dim3(S3 / 256), dim3(256), 0, stream>>>(x, pocc);
    k_fel1 <<<dim3(S3 * 16 / 256), dim3(256), 0, stream>>>(pocc, w_fel1, b_fel1, h1);
    k_fel2 <<<dim3(S3 * 16 / 256), dim3(256), 0, stream>>>(pocc, h1, w_fel2, b_fel2, h2);
    k_up   <<<dim3(S3 * 8 / 256), dim3(256), 0, stream>>>(pocc, h2, w_up, b_up, probf16);
    k_masks<<<dim3(16, 64), dim3(64, 4), 0, stream>>>(x, pocc, lw_in, lw_fin, out + (size_t)8 * G3);
    k_prep_bfrag<<<dim3(8, 75), dim3(64), 0, stream>>>(wc1, wl1, bfrag);

    k_conv1_mfma<<<dim3(1024, 8), dim3(64, 4), 0, stream>>>(
        probf16, lw_in, bfrag, bc1, bl1, hbase);
    k_conv2_all<<<dim3(1024, 8), dim3(64, 4), 0, stream>>>(
        (const u32*)hbase, lw_in, lw_fin, wc2, bc2, wl2, bl2, out);
}